// Round 1
// baseline (589.846 us; speedup 1.0000x reference)
//
#include <hip/hip_runtime.h>
#include <math.h>

#define N 4096
#define D 128
#define RPB 4            // rows per block
#define NTHREADS 256
#define KSEL 32          // 0-indexed order statistic (33rd smallest)
#define ALPHA_C 16.0f

__device__ inline float waveSum(float v){
  #pragma unroll
  for (int o = 32; o; o >>= 1) v += __shfl_xor(v, o);
  return v;
}
__device__ inline float waveMin(float v){
  #pragma unroll
  for (int o = 32; o; o >>= 1) v = fminf(v, __shfl_xor(v, o));
  return v;
}

// block-wide sum/min over 256 threads (4 waves); scr must hold 4 floats
__device__ inline float blockSum(float v, float* scr){
  int lane = threadIdx.x & 63, w = threadIdx.x >> 6;
  v = waveSum(v);
  __syncthreads();
  if (lane == 0) scr[w] = v;
  __syncthreads();
  return scr[0] + scr[1] + scr[2] + scr[3];
}
__device__ inline float blockMin(float v, float* scr){
  int lane = threadIdx.x & 63, w = threadIdx.x >> 6;
  v = waveMin(v);
  __syncthreads();
  if (lane == 0) scr[w] = v;
  __syncthreads();
  return fminf(fminf(scr[0], scr[1]), fminf(scr[2], scr[3]));
}

// order-preserving float->uint key (handles negatives)
__device__ inline unsigned fkey(float f){
  unsigned u = __float_as_uint(f);
  return u ^ ((u >> 31) ? 0xFFFFFFFFu : 0x80000000u);
}
__device__ inline float fkey_inv(unsigned u){
  unsigned bits = (u & 0x80000000u) ? (u ^ 0x80000000u) : ~u;
  return __uint_as_float(bits);
}

// --- kernel 1: row-normalize, write xn and sq (= sum of normalized squares)
__global__ __launch_bounds__(64) void knorm(const float* __restrict__ in,
                                            float* __restrict__ xn,
                                            float* __restrict__ sq){
  int row = blockIdx.x;
  int lane = threadIdx.x;
  const float* p = in + (size_t)row * D;
  float e0 = p[lane], e1 = p[lane + 64];
  float s = waveSum(e0*e0 + e1*e1);
  float inv = 1.0f / sqrtf(s);
  float x0 = e0 * inv, x1 = e1 * inv;
  float s2 = waveSum(x0*x0 + x1*x1);   // faithful: sq from normalized x
  float* q = xn + (size_t)row * D;
  q[lane] = x0; q[lane + 64] = x1;
  if (lane == 0) sq[row] = s2;
}

// --- kernel 2: per-row distances, radix-select thr, masked exp sums
__global__ __launch_bounds__(NTHREADS) void kmain(const float* __restrict__ xn,
                                                  const float* __restrict__ sq,
                                                  const int* __restrict__ tgt,
                                                  double* __restrict__ accum){
  __shared__ float xi[RPB][D];          // 2 KB
  __shared__ float dist[RPB][N];        // 64 KB
  __shared__ unsigned hist[256];        // 1 KB
  __shared__ float scr[4];
  __shared__ int kkSh, chosenSh;
  __shared__ float baseSh[RPB], minposSh[RPB];

  const int tid = threadIdx.x;
  const int i0 = blockIdx.x * RPB;

  // stage the RPB query rows into LDS (coalesced)
  for (int t = tid; t < RPB * D; t += NTHREADS)
    (&xi[0][0])[t] = xn[(size_t)i0 * D + t];
  __syncthreads();

  float sqi[RPB]; int ti[RPB];
  #pragma unroll
  for (int r = 0; r < RPB; ++r){ sqi[r] = sq[i0 + r]; ti[r] = tgt[i0 + r]; }

  // ---- pass 1: distances + streaming stats
  float bsum[RPB] = {0.f, 0.f, 0.f, 0.f};
  float mpos[RPB] = {INFINITY, INFINITY, INFINITY, INFINITY};
  float posd = 0.f, negd = 0.f;

  for (int j = tid; j < N; j += NTHREADS){
    const float4* xj = (const float4*)(xn + (size_t)j * D);
    float dot[RPB] = {0.f, 0.f, 0.f, 0.f};
    #pragma unroll
    for (int k = 0; k < D/4; ++k){
      float4 v = xj[k];
      #pragma unroll
      for (int r = 0; r < RPB; ++r){
        float4 u = ((const float4*)xi[r])[k];   // LDS broadcast read
        dot[r] += u.x*v.x + u.y*v.y + u.z*v.z + u.w*v.w;
      }
    }
    float sqj = sq[j]; int tj = tgt[j];
    #pragma unroll
    for (int r = 0; r < RPB; ++r){
      float dj = sqi[r] + sqj - 2.0f * dot[r];
      dist[r][j] = dj;
      bsum[r] += dj;                      // base includes diagonal (~0), like ref
      bool same = (tj == ti[r]);
      bool diag = (j == i0 + r);
      if (same && !diag){ posd += dj; mpos[r] = fminf(mpos[r], dj); }
      if (!same) negd += dj;
    }
  }
  __syncthreads();

  #pragma unroll
  for (int r = 0; r < RPB; ++r){
    float b = blockSum(bsum[r], scr);
    float m = blockMin(mpos[r], scr);
    if (tid == 0){ baseSh[r] = b / (float)N; minposSh[r] = m; }
  }
  float posdT = blockSum(posd, scr);
  float negdT = blockSum(negd, scr);
  if (tid == 0){
    atomicAdd(&accum[2], (double)posdT);
    atomicAdd(&accum[3], (double)negdT);
  }
  __syncthreads();

  // ---- per row: radix select 33rd smallest (diag keyed to max), then logits
  for (int r = 0; r < RPB; ++r){
    const int irow = i0 + r;
    unsigned prefix = 0, pmask = 0;
    if (tid == 0) kkSh = KSEL;

    for (int shift = 24; shift >= 0; shift -= 8){
      hist[tid] = 0;
      __syncthreads();
      for (int j = tid; j < N; j += NTHREADS){
        unsigned key = (j == irow) ? 0xFFFFFFFFu : fkey(dist[r][j]);
        if ((key & pmask) == prefix)
          atomicAdd(&hist[(key >> shift) & 255u], 1u);
      }
      __syncthreads();
      if (tid < 64){
        int b0 = tid * 4;
        unsigned c[4] = {hist[b0], hist[b0+1], hist[b0+2], hist[b0+3]};
        unsigned lsum = c[0] + c[1] + c[2] + c[3];
        unsigned incl = lsum;
        #pragma unroll
        for (int off = 1; off < 64; off <<= 1){
          unsigned t = __shfl_up(incl, off);
          if (tid >= off) incl += t;
        }
        unsigned acc = incl - lsum;       // exclusive prefix
        int kk = kkSh;                    // read before any write (in-order wave)
        #pragma unroll
        for (int q = 0; q < 4; ++q){
          if ((unsigned)kk >= acc && (unsigned)kk < acc + c[q]){
            chosenSh = b0 + q;
            kkSh = kk - (int)acc;
          }
          acc += c[q];
        }
      }
      __syncthreads();
      prefix |= ((unsigned)chosenSh) << shift;
      pmask  |= 0xFFu << shift;
    }

    const float thr = fkey_inv(prefix);   // exact 33rd-smallest value
    const float base = baseSh[r];

    float pls = 0.f, nls = 0.f, pcnt = 0.f;
    for (int j = tid; j < N; j += NTHREADS){
      float dj = dist[r][j];
      if (dj < thr){                      // strict, matching reference
        bool same = (tgt[j] == ti[r]);
        if (same){
          if (j != irow){ float e = expf(ALPHA_C * (base - dj)); pls += e; pcnt += 1.f; }
        } else {
          nls += expf(ALPHA_C * (base - dj));
        }
      }
    }
    pls  = blockSum(pls,  scr);
    nls  = blockSum(nls,  scr);
    pcnt = blockSum(pcnt, scr);
    if (tid == 0){
      float plogit = (pcnt > 0.f) ? pls : expf(ALPHA_C * (base - minposSh[r]));
      float loss_i = -logf(plogit / (plogit + nls));
      atomicAdd(&accum[0], (double)loss_i);
      atomicAdd(&accum[1], (loss_i < 0.6f) ? 1.0 : 0.0);
    }
    __syncthreads();
  }
}

// --- kernel 3: finalize the 4 scalars
__global__ void kfinal(const double* __restrict__ accum, float* __restrict__ out){
  out[0] = (float)(accum[0] / (double)N);                       // loss
  out[1] = (float)(accum[1] / (double)N);                       // accuracy
  out[2] = (float)(accum[2] / ((double)N * 7.0));               // pos_d
  out[3] = (float)(accum[3] / ((double)N * (double)(N - 8)));   // neg_d
}

extern "C" void kernel_launch(void* const* d_in, const int* in_sizes, int n_in,
                              void* d_out, int out_size, void* d_ws, size_t ws_size,
                              hipStream_t stream){
  (void)in_sizes; (void)n_in; (void)out_size; (void)ws_size;
  const float* in  = (const float*)d_in[0];
  const int*   tgt = (const int*)d_in[1];
  float* out = (float*)d_out;

  float*  xn    = (float*)d_ws;                  // N*D floats (2 MB)
  float*  sq    = xn + (size_t)N * D;            // N floats
  double* accum = (double*)(sq + N);             // 4 doubles (8B-aligned: offset 2113536)

  hipMemsetAsync(accum, 0, 4 * sizeof(double), stream);
  knorm <<<N, 64, 0, stream>>>(in, xn, sq);
  kmain <<<N / RPB, NTHREADS, 0, stream>>>(xn, sq, tgt, accum);
  kfinal<<<1, 1, 0, stream>>>(accum, out);
}

// Round 2
// 368.517 us; speedup vs baseline: 1.6006x; 1.6006x over previous
//
#include <hip/hip_runtime.h>
#include <math.h>

#define N 4096
#define D 128
#define RPB 8            // rows per block
#define NT 512           // threads per block (8 waves; wave w owns row w)
#define KSEL 32          // 0-indexed order statistic (33rd smallest)
#define CAND 320         // candidate buffer per row
#define ALPHA_C 16.0f

__device__ inline float waveSumF(float v){
  #pragma unroll
  for (int o = 32; o; o >>= 1) v += __shfl_xor(v, o);
  return v;
}
__device__ inline int waveSumI(int v){
  #pragma unroll
  for (int o = 32; o; o >>= 1) v += __shfl_xor(v, o);
  return v;
}
__device__ inline float waveMinF(float v){
  #pragma unroll
  for (int o = 32; o; o >>= 1) v = fminf(v, __shfl_xor(v, o));
  return v;
}

// order-preserving float->uint key (monotone bijection)
__device__ inline unsigned fkey(float f){
  unsigned u = __float_as_uint(f);
  return u ^ ((u >> 31) ? 0xFFFFFFFFu : 0x80000000u);
}
__device__ inline float fkey_inv(unsigned u){
  unsigned bits = (u & 0x80000000u) ? (u ^ 0x80000000u) : ~u;
  return __uint_as_float(bits);
}

// --- kernel 1: row-normalize, write xn and sq (wave per row)
__global__ __launch_bounds__(256) void knorm(const float* __restrict__ in,
                                             float* __restrict__ xn,
                                             float* __restrict__ sq){
  int row = blockIdx.x * 4 + (threadIdx.x >> 6);
  int lane = threadIdx.x & 63;
  const float* p = in + (size_t)row * D;
  float e0 = p[lane], e1 = p[lane + 64];
  float s = waveSumF(e0*e0 + e1*e1);
  float inv = 1.0f / sqrtf(s);
  float x0 = e0 * inv, x1 = e1 * inv;
  float s2 = waveSumF(x0*x0 + x1*x1);    // faithful: sq from normalized x
  float* q = xn + (size_t)row * D;
  q[lane] = x0; q[lane + 64] = x1;
  if (lane == 0) sq[row] = s2;
}

// --- kernel 2: distances + exact selection + logits
__global__ __launch_bounds__(NT, 2) void kmain(const float* __restrict__ xn,
                                               const float* __restrict__ sq,
                                               const int* __restrict__ tgt,
                                               double* __restrict__ accum){
  __shared__ float dist[RPB][N];        // 128 KB
  __shared__ float xi[RPB][D];          // 4 KB
  __shared__ float cand[RPB][CAND];     // 10 KB
  __shared__ int   ccnt[RPB];
  __shared__ float scr2[8][RPB + 2];    // per-wave row-sums + posd + negd
  __shared__ float scr3[8][RPB];        // per-wave row-mins
  __shared__ float baseSh[RPB], minposSh[RPB], lsSh[RPB], acSh[RPB];

  const int tid  = threadIdx.x;
  const int lane = tid & 63;
  const int w    = tid >> 6;            // wave id == row id in per-wave phase
  const int i0   = blockIdx.x * RPB;

  // stage query rows into LDS; init counters
  for (int t = tid; t < RPB * D; t += NT)
    (&xi[0][0])[t] = xn[(size_t)i0 * D + t];
  if (tid < RPB) ccnt[tid] = 0;
  __syncthreads();

  float sqi[RPB]; int ti[RPB];
  #pragma unroll
  for (int r = 0; r < RPB; ++r){ sqi[r] = sq[i0 + r]; ti[r] = tgt[i0 + r]; }

  // ---- pass 1: dot products (j-register-blocked x4) + streaming stats
  float bsum[RPB];
  float mpos[RPB];
  #pragma unroll
  for (int r = 0; r < RPB; ++r){ bsum[r] = 0.f; mpos[r] = INFINITY; }
  float posd = 0.f, negd = 0.f;

  #pragma unroll 1
  for (int jb = 0; jb < 2; ++jb){
    float dot[RPB][4];
    #pragma unroll
    for (int r = 0; r < RPB; ++r)
      { dot[r][0]=0.f; dot[r][1]=0.f; dot[r][2]=0.f; dot[r][3]=0.f; }

    const float4* b0 = (const float4*)(xn + ((size_t)(jb*2048) + tid) * D);
    const float4* b1 = b0 + 512  * (D/4);
    const float4* b2 = b0 + 1024 * (D/4);
    const float4* b3 = b0 + 1536 * (D/4);

    for (int k = 0; k < D/4; ++k){
      float4 v0 = b0[k], v1 = b1[k], v2 = b2[k], v3 = b3[k];
      #pragma unroll
      for (int r = 0; r < RPB; ++r){
        float4 u = ((const float4*)xi[r])[k];
        dot[r][0] += u.x*v0.x + u.y*v0.y + u.z*v0.z + u.w*v0.w;
        dot[r][1] += u.x*v1.x + u.y*v1.y + u.z*v1.z + u.w*v1.w;
        dot[r][2] += u.x*v2.x + u.y*v2.y + u.z*v2.z + u.w*v2.w;
        dot[r][3] += u.x*v3.x + u.y*v3.y + u.z*v3.z + u.w*v3.w;
      }
    }
    #pragma unroll
    for (int jj = 0; jj < 4; ++jj){
      int j = jb*2048 + jj*512 + tid;
      float sqj = sq[j]; int tj = tgt[j];
      #pragma unroll
      for (int r = 0; r < RPB; ++r){
        float dj = sqi[r] + sqj - 2.0f * dot[r][jj];
        bsum[r] += dj;                    // base includes true diag value (ref)
        bool same = (tj == ti[r]);
        bool diag = (j == i0 + r);
        if (same && !diag){ posd += dj; mpos[r] = fminf(mpos[r], dj); }
        if (!same) negd += dj;
        dist[r][j] = diag ? INFINITY : dj; // inf on diag for select/logits
      }
    }
  }

  // ---- stats reduce (2 barriers total)
  #pragma unroll
  for (int r = 0; r < RPB; ++r){
    float v = waveSumF(bsum[r]); if (lane == 0) scr2[w][r] = v;
    float m = waveMinF(mpos[r]); if (lane == 0) scr3[w][r] = m;
  }
  { float v = waveSumF(posd); if (lane == 0) scr2[w][RPB]   = v; }
  { float v = waveSumF(negd); if (lane == 0) scr2[w][RPB+1] = v; }
  __syncthreads();
  if (tid < RPB){
    float s = 0.f, m = INFINITY;
    #pragma unroll
    for (int q = 0; q < 8; ++q){ s += scr2[q][tid]; m = fminf(m, scr3[q][tid]); }
    baseSh[tid]   = s * (1.0f / (float)N);
    minposSh[tid] = m;
  }
  if (tid == RPB){
    float s = 0.f;
    #pragma unroll
    for (int q = 0; q < 8; ++q) s += scr2[q][RPB];
    atomicAdd(&accum[2], (double)s);
  }
  if (tid == RPB + 1){
    float s = 0.f;
    #pragma unroll
    for (int q = 0; q < 8; ++q) s += scr2[q][RPB+1];
    atomicAdd(&accum[3], (double)s);
  }
  __syncthreads();

  // ---- per-wave phase: wave w owns row w. No block barriers below until end.
  {
    const float4* drow = (const float4*)dist[w];
    unsigned lo = fkey(-0.5f);   // cnt(dist < -0.5) == 0 guaranteed
    unsigned hi = fkey(4.5f);    // cnt(dist <  4.5) == 4095 >= 33 guaranteed
    float thr;
    int   c = 0;
    bool  collected = false;

    while (hi - lo > 1u){
      unsigned mid = lo + ((hi - lo) >> 1);
      float pv = fkey_inv(mid);
      int cc = 0;
      #pragma unroll
      for (int t = 0; t < 16; ++t){
        float4 v = drow[lane + 64*t];
        cc += (v.x < pv) + (v.y < pv) + (v.z < pv) + (v.w < pv);
      }
      cc = waveSumI(cc);
      if (cc < KSEL + 1) lo = mid;
      else { hi = mid; if (cc <= CAND){ collected = true; c = cc; break; } }
    }

    if (collected){
      float pv = fkey_inv(hi);
      #pragma unroll
      for (int t = 0; t < 16; ++t){
        float4 v = drow[lane + 64*t];
        if (v.x < pv){ int ix = atomicAdd(&ccnt[w],1); if (ix < CAND) cand[w][ix] = v.x; }
        if (v.y < pv){ int ix = atomicAdd(&ccnt[w],1); if (ix < CAND) cand[w][ix] = v.y; }
        if (v.z < pv){ int ix = atomicAdd(&ccnt[w],1); if (ix < CAND) cand[w][ix] = v.z; }
        if (v.w < pv){ int ix = atomicAdd(&ccnt[w],1); if (ix < CAND) cand[w][ix] = v.w; }
      }
      __threadfence_block();            // drain this wave's LDS writes
      // exact rank select: unique (value, idx) with rank == KSEL
      float my[5]; int nm = 0;
      for (int t = lane; t < c; t += 64) my[nm++] = cand[w][t];
      for (int m = 0; m < nm; ++m){
        int myidx = lane + 64*m;
        float v = my[m];
        int rank = 0;
        for (int q = 0; q < c; ++q){
          float cq = cand[w][q];        // broadcast read
          rank += (cq < v) || (cq == v && q < myidx);
        }
        if (rank == KSEL) minposSh[w] == minposSh[w] ? (cand[w][CAND-1] = v) : 0.0f; // placeholder avoided below
        if (rank == KSEL) lsSh[w] = v;  // reuse lsSh as thr mailbox (overwritten later)
      }
      __threadfence_block();
      thr = lsSh[w];
    } else {
      thr = fkey_inv(lo);               // fully converged: key(lo) is the K-th value
    }

    // ---- logits for row w (strict '<', diag is INF so auto-excluded)
    const float base = baseSh[w];
    const int   tw   = ti[w];
    float pls = 0.f, nls = 0.f; int pcnt = 0;
    #pragma unroll 4
    for (int t = 0; t < 16; ++t){
      float4 v = drow[lane + 64*t];
      int j0 = (lane + 64*t) * 4;
      if (v.x < thr){ float e = expf(ALPHA_C*(base - v.x)); if (tgt[j0  ] == tw){ pls += e; pcnt++; } else nls += e; }
      if (v.y < thr){ float e = expf(ALPHA_C*(base - v.y)); if (tgt[j0+1] == tw){ pls += e; pcnt++; } else nls += e; }
      if (v.z < thr){ float e = expf(ALPHA_C*(base - v.z)); if (tgt[j0+2] == tw){ pls += e; pcnt++; } else nls += e; }
      if (v.w < thr){ float e = expf(ALPHA_C*(base - v.w)); if (tgt[j0+3] == tw){ pls += e; pcnt++; } else nls += e; }
    }
    pls = waveSumF(pls); nls = waveSumF(nls); pcnt = waveSumI(pcnt);
    if (lane == 0){
      float plogit = (pcnt > 0) ? pls : expf(ALPHA_C*(base - minposSh[w]));
      float li = -logf(plogit / (plogit + nls));
      lsSh[w] = li;
      acSh[w] = (li < 0.6f) ? 1.f : 0.f;
    }
  }
  __syncthreads();
  if (tid == 0){
    float ls = 0.f, ac = 0.f;
    #pragma unroll
    for (int r = 0; r < RPB; ++r){ ls += lsSh[r]; ac += acSh[r]; }
    atomicAdd(&accum[0], (double)ls);
    atomicAdd(&accum[1], (double)ac);
  }
}

// --- kernel 3: finalize
__global__ void kfinal(const double* __restrict__ accum, float* __restrict__ out){
  out[0] = (float)(accum[0] / (double)N);
  out[1] = (float)(accum[1] / (double)N);
  out[2] = (float)(accum[2] / ((double)N * 7.0));
  out[3] = (float)(accum[3] / ((double)N * (double)(N - 8)));
}

extern "C" void kernel_launch(void* const* d_in, const int* in_sizes, int n_in,
                              void* d_out, int out_size, void* d_ws, size_t ws_size,
                              hipStream_t stream){
  (void)in_sizes; (void)n_in; (void)out_size; (void)ws_size;
  const float* in  = (const float*)d_in[0];
  const int*   tgt = (const int*)d_in[1];
  float* out = (float*)d_out;

  float*  xn    = (float*)d_ws;                  // N*D floats
  float*  sq    = xn + (size_t)N * D;            // N floats
  double* accum = (double*)(sq + N);             // 4 doubles (8B aligned)

  hipMemsetAsync(accum, 0, 4 * sizeof(double), stream);
  knorm <<<N/4, 256, 0, stream>>>(in, xn, sq);
  kmain <<<N/RPB, NT, 0, stream>>>(xn, sq, tgt, accum);
  kfinal<<<1, 1, 0, stream>>>(accum, out);
}

// Round 3
// 195.639 us; speedup vs baseline: 3.0150x; 1.8837x over previous
//
#include <hip/hip_runtime.h>
#include <math.h>

#define N 4096
#define D 128
#define RPB 8            // rows per block
#define NT 512           // threads per block (8 waves; wave w owns row w in scans)
#define KSEL 32          // 0-indexed order statistic (33rd smallest)
#define CAND 320         // candidate buffer per row
#define ALPHA_C 16.0f

__device__ inline float waveSumF(float v){
  #pragma unroll
  for (int o = 32; o; o >>= 1) v += __shfl_xor(v, o);
  return v;
}
__device__ inline int waveSumI(int v){
  #pragma unroll
  for (int o = 32; o; o >>= 1) v += __shfl_xor(v, o);
  return v;
}
__device__ inline float waveMinF(float v){
  #pragma unroll
  for (int o = 32; o; o >>= 1) v = fminf(v, __shfl_xor(v, o));
  return v;
}

// order-preserving float->uint key (monotone bijection)
__device__ inline unsigned fkey(float f){
  unsigned u = __float_as_uint(f);
  return u ^ ((u >> 31) ? 0xFFFFFFFFu : 0x80000000u);
}
__device__ inline float fkey_inv(unsigned u){
  unsigned bits = (u & 0x80000000u) ? (u ^ 0x80000000u) : ~u;
  return __uint_as_float(bits);
}

// --- kernel 1: row-normalize; write xn (row-major), xnT (transposed), sq
__global__ __launch_bounds__(256) void knorm(const float* __restrict__ in,
                                             float* __restrict__ xn,
                                             float* __restrict__ xnT,
                                             float* __restrict__ sq){
  int row = blockIdx.x * 4 + (threadIdx.x >> 6);
  int lane = threadIdx.x & 63;
  const float* p = in + (size_t)row * D;
  float e0 = p[lane], e1 = p[lane + 64];
  float s = waveSumF(e0*e0 + e1*e1);
  float inv = 1.0f / sqrtf(s);
  float x0 = e0 * inv, x1 = e1 * inv;
  float s2 = waveSumF(x0*x0 + x1*x1);     // faithful: sq from normalized x
  xn[(size_t)row * D + lane]      = x0;
  xn[(size_t)row * D + lane + 64] = x1;
  xnT[(size_t)lane * N + row]        = x0;   // scattered, tiny total traffic
  xnT[(size_t)(lane + 64) * N + row] = x1;
  if (lane == 0) sq[row] = s2;
}

// --- kernel 2: distances (coalesced via xnT) + exact selection + logits
__global__ __launch_bounds__(NT, 2) void kmain(const float* __restrict__ xn,
                                               const float* __restrict__ xnT,
                                               const float* __restrict__ sq,
                                               const int* __restrict__ tgt,
                                               double* __restrict__ accum){
  __shared__ float dist[RPB][N];        // 128 KB
  __shared__ float xi[RPB][D];          // 4 KB
  __shared__ float cand[RPB][CAND];     // 10 KB
  __shared__ int   ccnt[RPB];
  __shared__ float scr2[8][RPB + 2];
  __shared__ float scr3[8][RPB];
  __shared__ float baseSh[RPB], minposSh[RPB], lsSh[RPB], acSh[RPB];

  const int tid  = threadIdx.x;
  const int lane = tid & 63;
  const int w    = tid >> 6;
  const int i0   = blockIdx.x * RPB;

  for (int t = tid; t < RPB * D; t += NT)
    (&xi[0][0])[t] = xn[(size_t)i0 * D + t];
  if (tid < RPB) ccnt[tid] = 0;
  __syncthreads();

  float sqi[RPB]; int ti[RPB];
  #pragma unroll
  for (int r = 0; r < RPB; ++r){ sqi[r] = sq[i0 + r]; ti[r] = tgt[i0 + r]; }

  // ---- dot pass: lane covers j in {jA..jA+3} u {jB..jB+3}; streaming xnT
  // jA = 512*w + 4*lane, jB = jA + 256. Wave-load = contiguous 1KB segment.
  const int jA = 512 * w + 4 * lane;
  const int jB = jA + 256;
  const float4* T4 = (const float4*)xnT;
  const int fA = 128 * w + lane;        // float4 index of cols jA.. within a k-row
  const int fB = fA + 64;

  float acc[RPB][8];
  #pragma unroll
  for (int r = 0; r < RPB; ++r)
    #pragma unroll
    for (int q = 0; q < 8; ++q) acc[r][q] = 0.f;

  for (int k = 0; k < D; ++k){
    float4 vA = T4[(size_t)k * (N/4) + fA];
    float4 vB = T4[(size_t)k * (N/4) + fB];
    float xik[RPB];
    #pragma unroll
    for (int r = 0; r < RPB; ++r) xik[r] = xi[r][k];   // LDS broadcast
    #pragma unroll
    for (int r = 0; r < RPB; ++r){
      acc[r][0] += xik[r] * vA.x;  acc[r][1] += xik[r] * vA.y;
      acc[r][2] += xik[r] * vA.z;  acc[r][3] += xik[r] * vA.w;
      acc[r][4] += xik[r] * vB.x;  acc[r][5] += xik[r] * vB.y;
      acc[r][6] += xik[r] * vB.z;  acc[r][7] += xik[r] * vB.w;
    }
  }

  // ---- epilogue: dist + streaming stats
  float4 sqA = ((const float4*)sq)[fA], sqB = ((const float4*)sq)[fB];
  int4   tgA = ((const int4*)tgt)[fA],  tgB = ((const int4*)tgt)[fB];
  float sqj[8] = {sqA.x,sqA.y,sqA.z,sqA.w, sqB.x,sqB.y,sqB.z,sqB.w};
  int   tj [8] = {tgA.x,tgA.y,tgA.z,tgA.w, tgB.x,tgB.y,tgB.z,tgB.w};

  float bsum[RPB], mpos[RPB];
  #pragma unroll
  for (int r = 0; r < RPB; ++r){ bsum[r] = 0.f; mpos[r] = INFINITY; }
  float posd = 0.f, negd = 0.f;

  #pragma unroll
  for (int r = 0; r < RPB; ++r){
    float dv[8];
    #pragma unroll
    for (int q = 0; q < 8; ++q){
      int j = (q < 4) ? (jA + q) : (jB + q - 4);
      float dj = sqi[r] + sqj[q] - 2.0f * acc[r][q];
      bsum[r] += dj;                       // base includes true diag value
      bool same = (tj[q] == ti[r]);
      bool diag = (j == i0 + r);
      if (same && !diag){ posd += dj; mpos[r] = fminf(mpos[r], dj); }
      if (!same) negd += dj;
      dv[q] = diag ? INFINITY : dj;        // inf on diag for select/logits
    }
    ((float4*)&dist[r][jA])[0] = make_float4(dv[0], dv[1], dv[2], dv[3]);
    ((float4*)&dist[r][jB])[0] = make_float4(dv[4], dv[5], dv[6], dv[7]);
  }

  // ---- stats reduce
  #pragma unroll
  for (int r = 0; r < RPB; ++r){
    float v = waveSumF(bsum[r]); if (lane == 0) scr2[w][r] = v;
    float m = waveMinF(mpos[r]); if (lane == 0) scr3[w][r] = m;
  }
  { float v = waveSumF(posd); if (lane == 0) scr2[w][RPB]   = v; }
  { float v = waveSumF(negd); if (lane == 0) scr2[w][RPB+1] = v; }
  __syncthreads();
  if (tid < RPB){
    float s = 0.f, m = INFINITY;
    #pragma unroll
    for (int q = 0; q < 8; ++q){ s += scr2[q][tid]; m = fminf(m, scr3[q][tid]); }
    baseSh[tid]   = s * (1.0f / (float)N);
    minposSh[tid] = m;
  }
  if (tid == RPB){
    float s = 0.f;
    #pragma unroll
    for (int q = 0; q < 8; ++q) s += scr2[q][RPB];
    atomicAdd(&accum[2], (double)s);
  }
  if (tid == RPB + 1){
    float s = 0.f;
    #pragma unroll
    for (int q = 0; q < 8; ++q) s += scr2[q][RPB+1];
    atomicAdd(&accum[3], (double)s);
  }
  __syncthreads();

  // ---- per-wave phase: wave w owns row w (exact R2 logic, proven absmax 0)
  {
    const float4* drow = (const float4*)dist[w];
    unsigned lo = fkey(-0.5f);
    unsigned hi = fkey(4.5f);
    float thr;
    int   c = 0;
    bool  collected = false;

    while (hi - lo > 1u){
      unsigned mid = lo + ((hi - lo) >> 1);
      float pv = fkey_inv(mid);
      int cc = 0;
      #pragma unroll
      for (int t = 0; t < 16; ++t){
        float4 v = drow[lane + 64*t];
        cc += (v.x < pv) + (v.y < pv) + (v.z < pv) + (v.w < pv);
      }
      cc = waveSumI(cc);
      if (cc < KSEL + 1) lo = mid;
      else { hi = mid; if (cc <= CAND){ collected = true; c = cc; break; } }
    }

    if (collected){
      float pv = fkey_inv(hi);
      #pragma unroll
      for (int t = 0; t < 16; ++t){
        float4 v = drow[lane + 64*t];
        if (v.x < pv){ int ix = atomicAdd(&ccnt[w],1); if (ix < CAND) cand[w][ix] = v.x; }
        if (v.y < pv){ int ix = atomicAdd(&ccnt[w],1); if (ix < CAND) cand[w][ix] = v.y; }
        if (v.z < pv){ int ix = atomicAdd(&ccnt[w],1); if (ix < CAND) cand[w][ix] = v.z; }
        if (v.w < pv){ int ix = atomicAdd(&ccnt[w],1); if (ix < CAND) cand[w][ix] = v.w; }
      }
      __threadfence_block();
      float my[5]; int nm = 0;
      for (int t = lane; t < c; t += 64) my[nm++] = cand[w][t];
      for (int m = 0; m < nm; ++m){
        int myidx = lane + 64*m;
        float v = my[m];
        int rank = 0;
        for (int q = 0; q < c; ++q){
          float cq = cand[w][q];
          rank += (cq < v) || (cq == v && q < myidx);
        }
        if (rank == KSEL) lsSh[w] = v;    // thr mailbox (unique winner)
      }
      __threadfence_block();
      thr = lsSh[w];
    } else {
      thr = fkey_inv(lo);                 // converged: exact 33rd-smallest
    }

    const float base = baseSh[w];
    const int   tw   = ti[w];
    float pls = 0.f, nls = 0.f; int pcnt = 0;
    #pragma unroll 4
    for (int t = 0; t < 16; ++t){
      float4 v = drow[lane + 64*t];
      int4 tg = ((const int4*)tgt)[lane + 64*t];
      if (v.x < thr){ float e = expf(ALPHA_C*(base - v.x)); if (tg.x == tw){ pls += e; pcnt++; } else nls += e; }
      if (v.y < thr){ float e = expf(ALPHA_C*(base - v.y)); if (tg.y == tw){ pls += e; pcnt++; } else nls += e; }
      if (v.z < thr){ float e = expf(ALPHA_C*(base - v.z)); if (tg.z == tw){ pls += e; pcnt++; } else nls += e; }
      if (v.w < thr){ float e = expf(ALPHA_C*(base - v.w)); if (tg.w == tw){ pls += e; pcnt++; } else nls += e; }
    }
    pls = waveSumF(pls); nls = waveSumF(nls); pcnt = waveSumI(pcnt);
    if (lane == 0){
      float plogit = (pcnt > 0) ? pls : expf(ALPHA_C*(base - minposSh[w]));
      float li = -logf(plogit / (plogit + nls));
      lsSh[w] = li;
      acSh[w] = (li < 0.6f) ? 1.f : 0.f;
    }
  }
  __syncthreads();
  if (tid == 0){
    float ls = 0.f, ac = 0.f;
    #pragma unroll
    for (int r = 0; r < RPB; ++r){ ls += lsSh[r]; ac += acSh[r]; }
    atomicAdd(&accum[0], (double)ls);
    atomicAdd(&accum[1], (double)ac);
  }
}

// --- kernel 3: finalize
__global__ void kfinal(const double* __restrict__ accum, float* __restrict__ out){
  out[0] = (float)(accum[0] / (double)N);
  out[1] = (float)(accum[1] / (double)N);
  out[2] = (float)(accum[2] / ((double)N * 7.0));
  out[3] = (float)(accum[3] / ((double)N * (double)(N - 8)));
}

extern "C" void kernel_launch(void* const* d_in, const int* in_sizes, int n_in,
                              void* d_out, int out_size, void* d_ws, size_t ws_size,
                              hipStream_t stream){
  (void)in_sizes; (void)n_in; (void)out_size; (void)ws_size;
  const float* in  = (const float*)d_in[0];
  const int*   tgt = (const int*)d_in[1];
  float* out = (float*)d_out;

  float*  xn    = (float*)d_ws;                    // N*D floats (2 MB)
  float*  xnT   = xn  + (size_t)N * D;             // D*N floats (2 MB)
  float*  sq    = xnT + (size_t)N * D;             // N floats
  double* accum = (double*)(sq + N);               // 4 doubles (8B aligned)

  hipMemsetAsync(accum, 0, 4 * sizeof(double), stream);
  knorm <<<N/4, 256, 0, stream>>>(in, xn, xnT, sq);
  kmain <<<N/RPB, NT, 0, stream>>>(xn, xnT, sq, tgt, accum);
  kfinal<<<1, 1, 0, stream>>>(accum, out);
}

// Round 4
// 193.965 us; speedup vs baseline: 3.0410x; 1.0086x over previous
//
#include <hip/hip_runtime.h>
#include <math.h>

#define N 4096
#define D 128
#define RPB 8            // rows per block == waves per block
#define NT 512
#define KSEL 32          // 0-indexed order statistic (33rd smallest)
#define CAND 192         // collect band [KSEL+1, CAND]
#define ALPHA_C 16.0f

__device__ inline float waveSumF(float v){
  #pragma unroll
  for (int o = 32; o; o >>= 1) v += __shfl_xor(v, o);
  return v;
}
__device__ inline int waveSumI(int v){
  #pragma unroll
  for (int o = 32; o; o >>= 1) v += __shfl_xor(v, o);
  return v;
}
__device__ inline float waveMinF(float v){
  #pragma unroll
  for (int o = 32; o; o >>= 1) v = fminf(v, __shfl_xor(v, o));
  return v;
}
// order-preserving float<->uint key (monotone bijection, adjacent keys = adjacent floats)
__device__ inline unsigned fkey(float f){
  unsigned u = __float_as_uint(f);
  return u ^ ((u >> 31) ? 0xFFFFFFFFu : 0x80000000u);
}
__device__ inline float fkey_inv(unsigned u){
  unsigned bits = (u & 0x80000000u) ? (u ^ 0x80000000u) : ~u;
  return __uint_as_float(bits);
}

// --- kernel 1: row-normalize; write xn, xnT, sq; zero accumulators
__global__ __launch_bounds__(256) void knorm(const float* __restrict__ in,
                                             float* __restrict__ xn,
                                             float* __restrict__ xnT,
                                             float* __restrict__ sq,
                                             double* __restrict__ accum,
                                             unsigned* __restrict__ ctr){
  if (blockIdx.x == 0 && threadIdx.x < 8){
    if (threadIdx.x < 4) accum[threadIdx.x] = 0.0;
    if (threadIdx.x == 4) *ctr = 0u;
  }
  int row = blockIdx.x * 4 + (threadIdx.x >> 6);
  int lane = threadIdx.x & 63;
  const float* p = in + (size_t)row * D;
  float e0 = p[lane], e1 = p[lane + 64];
  float s = waveSumF(e0*e0 + e1*e1);
  float inv = 1.0f / sqrtf(s);
  float x0 = e0 * inv, x1 = e1 * inv;
  float s2 = waveSumF(x0*x0 + x1*x1);      // faithful: sq from normalized x
  xn[(size_t)row * D + lane]      = x0;
  xn[(size_t)row * D + lane + 64] = x1;
  xnT[(size_t)lane * N + row]        = x0;
  xnT[(size_t)(lane + 64) * N + row] = x1;
  if (lane == 0) sq[row] = s2;
}

// --- kernel 2: dot pass + register transpose + register selection + logits
__global__ __launch_bounds__(NT, 4) void kmain(const float* __restrict__ xn,
                                               const float* __restrict__ xnT,
                                               const float* __restrict__ sq,
                                               const int* __restrict__ tgt,
                                               double* __restrict__ accum,
                                               unsigned* __restrict__ ctr,
                                               float* __restrict__ out){
  __shared__ float xi[RPB][D];            // 4 KB
  __shared__ float buf[2][RPB][512];      // 32 KB transpose tiles (dbuf)
  __shared__ float cand[RPB][CAND];       // 6 KB
  __shared__ int   ccnt[RPB];
  __shared__ float scrB[RPB][RPB];        // [src wave][row] base partial
  __shared__ float scrM[RPB][RPB];        // [src wave][row] minpos partial
  __shared__ float scrP[RPB], scrN[RPB], lsSh[RPB], acSh[RPB];

  const int tid  = threadIdx.x;
  const int lane = tid & 63;
  const int w    = tid >> 6;              // wave id == owned row in per-wave phase
  const int i0   = blockIdx.x * RPB;

  for (int t = tid; t < RPB * D; t += NT)
    (&xi[0][0])[t] = xn[(size_t)i0 * D + t];
  if (lane == 0){
    ccnt[w] = 0;
    #pragma unroll
    for (int t = 0; t < RPB; ++t){ scrB[w][t] = 0.f; scrM[w][t] = INFINITY; }
  }
  __syncthreads();

  // ---- dot pass (identical structure to R3; 64 acc/lane)
  const int fA = 128 * w + lane;          // float4 col index, j = 4*fA
  const int fB = fA + 64;
  const float4* T4 = (const float4*)xnT;

  float acc[RPB][8];
  #pragma unroll
  for (int r = 0; r < RPB; ++r)
    #pragma unroll
    for (int q = 0; q < 8; ++q) acc[r][q] = 0.f;

  for (int k = 0; k < D; ++k){
    float4 vA = T4[(size_t)k * (N/4) + fA];
    float4 vB = T4[(size_t)k * (N/4) + fB];
    float xik[RPB];
    #pragma unroll
    for (int r = 0; r < RPB; ++r) xik[r] = xi[r][k];   // LDS broadcast
    #pragma unroll
    for (int r = 0; r < RPB; ++r){
      acc[r][0] += xik[r] * vA.x;  acc[r][1] += xik[r] * vA.y;
      acc[r][2] += xik[r] * vA.z;  acc[r][3] += xik[r] * vA.w;
      acc[r][4] += xik[r] * vB.x;  acc[r][5] += xik[r] * vB.y;
      acc[r][6] += xik[r] * vB.z;  acc[r][7] += xik[r] * vB.w;
    }
  }

  // ---- 16 transpose rounds: wave w ends with row w in d[64]; stats fused.
  // d[4u+q] = dist[w][256u + 4*lane + q]
  float d[64];
  float posd = 0.f, negd = 0.f;

  #pragma unroll
  for (int rr = 0; rr < 16; ++rr){
    const int h = rr >> 3, t = rr & 7, A = rr & 1;
    const float sqi_t = sq[i0 + t];        // block-uniform
    const int   ti_t  = tgt[i0 + t];
    const int f = 128 * w + 64 * h + lane;
    const float4 sq4 = ((const float4*)sq)[f];
    const int4   tg4 = ((const int4*)tgt)[f];
    const int jbase = 4 * f;               // = 512w + 256h + 4*lane
    float dv[4]; float pb = 0.f, pm = INFINITY;
    #pragma unroll
    for (int q = 0; q < 4; ++q){
      float sqjq = (q==0)?sq4.x:(q==1)?sq4.y:(q==2)?sq4.z:sq4.w;
      int   tjq  = (q==0)?tg4.x:(q==1)?tg4.y:(q==2)?tg4.z:tg4.w;
      float dj = sqi_t + sqjq - 2.0f * acc[t][h*4 + q];
      pb += dj;                            // base includes true diag value (ref)
      bool same = (tjq == ti_t);
      bool diag = (jbase + q == i0 + t);
      if (same && !diag){ posd += dj; pm = fminf(pm, dj); }
      if (!same) negd += dj;
      dv[q] = diag ? INFINITY : dj;
    }
    float rb = waveSumF(pb);
    float rm = waveMinF(pm);
    if (lane == 0){ scrB[w][t] += rb; scrM[w][t] = fminf(scrM[w][t], rm); }
    ((float4*)&buf[A][w][4*lane])[0] = make_float4(dv[0], dv[1], dv[2], dv[3]);
    __syncthreads();                       // all round-rr writes done
    if (w == t){
      #pragma unroll
      for (int wp = 0; wp < 8; ++wp){
        float4 v = ((const float4*)&buf[A][wp][4*lane])[0];
        d[4*(2*wp + h) + 0] = v.x;  d[4*(2*wp + h) + 1] = v.y;
        d[4*(2*wp + h) + 2] = v.z;  d[4*(2*wp + h) + 3] = v.w;
      }
    }
    // next round writes the other buffer; __syncthreads (with its waitcnt drain)
    // before round rr+2 protects buffer reuse.
  }

  { float v = waveSumF(posd); if (lane == 0) scrP[w] = v; }
  { float v = waveSumF(negd); if (lane == 0) scrN[w] = v; }
  __syncthreads();

  // per-wave cross-wave-reduced stats for its own row
  float base, minpos;
  {
    float bp = (lane < 8) ? scrB[lane][w] : 0.f;
    base = waveSumF(bp) * (1.0f / (float)N);
    float mp = (lane < 8) ? scrM[lane][w] : INFINITY;
    minpos = waveMinF(mp);
  }
  if (tid == 0){
    double sp = 0.0, sn = 0.0;
    #pragma unroll
    for (int r = 0; r < RPB; ++r){ sp += (double)scrP[r]; sn += (double)scrN[r]; }
    atomicAdd(&accum[2], sp);
    atomicAdd(&accum[3], sn);
  }

  // ---- selection from registers (wave-local; no block barriers until end)
  float thr;
  {
    float dmin = INFINITY;
    #pragma unroll
    for (int s = 0; s < 64; ++s) dmin = fminf(dmin, d[s]);
    dmin = waveMinF(dmin);

    unsigned lo = fkey(dmin);              // cnt(d < dmin) == 0 < 33
    unsigned hi = fkey(4.5f);              // cnt == 4095 >= 33 (d <= 4+eps)
    int c = 0; bool have = false; float pvx = 0.f;

    while (hi - lo > 1u){
      float loV = fkey_inv(lo), hiV = fkey_inv(hi);
      unsigned mid = fkey(0.5f * (loV + hiV));      // value-space pivot
      mid = (mid <= lo) ? lo + 1u : ((mid >= hi) ? hi - 1u : mid);
      float pv = fkey_inv(mid);
      int cc = 0;
      #pragma unroll
      for (int s = 0; s < 64; ++s) cc += (d[s] < pv) ? 1 : 0;
      cc = waveSumI(cc);
      if (cc < KSEL + 1) lo = mid;
      else { hi = mid; if (cc <= CAND){ c = cc; have = true; pvx = pv; break; } }
    }

    if (have){
      #pragma unroll
      for (int s = 0; s < 64; ++s){
        if (d[s] < pvx){
          int ix = atomicAdd(&ccnt[w], 1);
          if (ix < CAND) cand[w][ix] = d[s];
        }
      }
      __threadfence_block();
      #pragma unroll
      for (int m = 0; m < 3; ++m){
        int idx = lane + 64 * m;
        if (idx < c){
          float v = cand[w][idx];
          int rank = 0;
          for (int q2 = 0; q2 < c; ++q2){
            float cq = cand[w][q2];                  // LDS broadcast
            rank += (cq < v) || (cq == v && q2 < idx);
          }
          if (rank == KSEL) lsSh[w] = v;             // unique-winner mailbox
        }
      }
      __threadfence_block();
      thr = lsSh[w];
    } else {
      thr = fkey_inv(lo);                            // exact 33rd smallest
    }
  }

  // ---- logits for row w (strict '<', diag is INF)
  {
    const int tw = tgt[i0 + w];
    float pls = 0.f, nls = 0.f; int pcnt = 0;
    #pragma unroll
    for (int u = 0; u < 16; ++u){
      int4 tg = ((const int4*)tgt)[64 * u + lane];
      #pragma unroll
      for (int q = 0; q < 4; ++q){
        float dvq = d[4*u + q];
        int   tjq = (q==0)?tg.x:(q==1)?tg.y:(q==2)?tg.z:tg.w;
        if (dvq < thr){
          float e = expf(ALPHA_C * (base - dvq));
          if (tjq == tw){ pls += e; pcnt++; } else nls += e;
        }
      }
    }
    pls = waveSumF(pls); nls = waveSumF(nls); pcnt = waveSumI(pcnt);
    if (lane == 0){
      float plogit = (pcnt > 0) ? pls : expf(ALPHA_C * (base - minpos));
      float li = -logf(plogit / (plogit + nls));
      lsSh[w] = li;
      acSh[w] = (li < 0.6f) ? 1.f : 0.f;
    }
  }
  __syncthreads();
  if (tid == 0){
    float ls = 0.f, ac = 0.f;
    #pragma unroll
    for (int r = 0; r < RPB; ++r){ ls += lsSh[r]; ac += acSh[r]; }
    atomicAdd(&accum[0], (double)ls);
    atomicAdd(&accum[1], (double)ac);
    // last-block finalize (replaces kfinal)
    __threadfence();
    unsigned done = atomicAdd(ctr, 1u);
    if (done == gridDim.x - 1){
      double a0 = atomicAdd(&accum[0], 0.0);
      double a1 = atomicAdd(&accum[1], 0.0);
      double a2 = atomicAdd(&accum[2], 0.0);
      double a3 = atomicAdd(&accum[3], 0.0);
      out[0] = (float)(a0 / (double)N);
      out[1] = (float)(a1 / (double)N);
      out[2] = (float)(a2 / ((double)N * 7.0));
      out[3] = (float)(a3 / ((double)N * (double)(N - 8)));
    }
  }
}

extern "C" void kernel_launch(void* const* d_in, const int* in_sizes, int n_in,
                              void* d_out, int out_size, void* d_ws, size_t ws_size,
                              hipStream_t stream){
  (void)in_sizes; (void)n_in; (void)out_size; (void)ws_size;
  const float* in  = (const float*)d_in[0];
  const int*   tgt = (const int*)d_in[1];
  float* out = (float*)d_out;

  float*    xn    = (float*)d_ws;                    // N*D floats (2 MB)
  float*    xnT   = xn  + (size_t)N * D;             // D*N floats (2 MB)
  float*    sq    = xnT + (size_t)N * D;             // N floats
  double*   accum = (double*)(sq + N);               // 4 doubles (8B aligned)
  unsigned* ctr   = (unsigned*)(accum + 4);

  knorm <<<N/4, 256, 0, stream>>>(in, xn, xnT, sq, accum, ctr);
  kmain <<<N/RPB, NT, 0, stream>>>(xn, xnT, sq, tgt, accum, ctr, out);
}